// Round 1
// baseline (46895.737 us; speedup 1.0000x reference)
//
#include <hip/hip_runtime.h>
#include <cstdint>
#include <cstddef>

// ---------------------------------------------------------------------------
// Parareal neural-ODE (MSZero_13761075216509)
// f(x) = tanh(x@W1 + b1) @ W2 ; Euler coarse / RK4 fine, 7 substeps, 3 outer
// iterations. fp32 emulated via bf16 hi/lo 3-term split on 16x16x32 MFMA.
// ---------------------------------------------------------------------------

typedef __attribute__((ext_vector_type(4))) float f32x4;
typedef __attribute__((ext_vector_type(8))) short s16x8;
typedef __attribute__((ext_vector_type(4))) unsigned short u16x4;

#define DEV __device__ __forceinline__

DEV unsigned short f2bf(float x) {
  union { float f; uint32_t u; } v; v.f = x;
  uint32_t r = v.u + 0x7FFFu + ((v.u >> 16) & 1u);   // RNE
  return (unsigned short)(r >> 16);
}
DEV float bf2f(unsigned short h) {
  union { uint32_t u; float f; } v; v.u = ((uint32_t)h) << 16; return v.f;
}
DEV void split2(float x, unsigned short &h, unsigned short &l) {
  h = f2bf(x);
  l = f2bf(x - bf2f(h));
}

// ---------------------------------------------------------------------------
// GEMM: C[M,N] = A[M,K] * B[K,N], A given as hi/lo bf16 [M][K] (row stride K),
// B given pre-transposed hi/lo bf16 [N][K] (row stride K).
// 3-term split: Ah*Bh + Ah*Bl + Al*Bh, fp32 accumulate.
// EPI=0: write F fp32 [M][N]
// EPI=1: v=tanh(acc+bias[col]); write Yh/Yl bf16 [M][N]
// EPI=2: write fp32 partial at Fout + blockIdx.z*M*N (split-K)
// Block: 256 thr = 4 waves (2x2), tile 128x128, BK=32, register-staged LDS.
// ---------------------------------------------------------------------------
template<int EPI>
__global__ __launch_bounds__(256, 2) void gemm_split_k(
    const unsigned short* __restrict__ Ah, const unsigned short* __restrict__ Al,
    const unsigned short* __restrict__ Bh, const unsigned short* __restrict__ Bl,
    const float* __restrict__ bias,
    float* __restrict__ Fout,
    unsigned short* __restrict__ Yh, unsigned short* __restrict__ Yl,
    int M, int N, int K, int KS)
{
  __shared__ unsigned short lA[2][128 * 32];
  __shared__ unsigned short lB[2][128 * 32];
  const int tid = threadIdx.x;
  const int w = tid >> 6, l = tid & 63;
  const int m0 = blockIdx.y * 128, n0 = blockIdx.x * 128;
  const size_t kbeg = (size_t)blockIdx.z * (size_t)KS;
  const int wm = (w >> 1) * 64, wn = (w & 1) * 64;

  f32x4 acc[4][4];
#pragma unroll
  for (int a = 0; a < 4; ++a)
#pragma unroll
    for (int b = 0; b < 4; ++b) acc[a][b] = (f32x4){0.f, 0.f, 0.f, 0.f};

  // staging: thread covers bytes [tid*16, +16) and [tid*16+4096, +16) of each
  // 8KB tile ([128 rows][32 k] bf16, 64 B/row)
  const int o0 = tid * 16;
  const int r0 = o0 >> 6;              // row 0..63
  const int c0 = (o0 & 63) >> 1;       // k-elem 0/8/16/24
  const size_t strideA = (size_t)64 * (size_t)K;
  const unsigned short* pah = Ah + (size_t)(m0 + r0) * K + kbeg + c0;
  const unsigned short* pal = Al + (size_t)(m0 + r0) * K + kbeg + c0;
  const unsigned short* pbh = Bh + (size_t)(n0 + r0) * K + kbeg + c0;
  const unsigned short* pbl = Bl + (size_t)(n0 + r0) * K + kbeg + c0;
  const int u0 = tid * 8, u1 = u0 + 2048;   // ushort indices in tile

  s16x8 vah0, vah1, val0, val1, vbh0, vbh1, vbl0, vbl1;
  auto LOADALL = [&](size_t ko) {
    vah0 = *(const s16x8*)(pah + ko); vah1 = *(const s16x8*)(pah + ko + strideA);
    val0 = *(const s16x8*)(pal + ko); val1 = *(const s16x8*)(pal + ko + strideA);
    vbh0 = *(const s16x8*)(pbh + ko); vbh1 = *(const s16x8*)(pbh + ko + strideA);
    vbl0 = *(const s16x8*)(pbl + ko); vbl1 = *(const s16x8*)(pbl + ko + strideA);
  };

  const int nk = KS >> 5;
  LOADALL(0);

  // fragment: lane l reads row (l&15) of its 16-row group, k = (l>>4)*8..+7
  const int aoff = (l & 15) * 32 + (l >> 4) * 8;

  for (int kt = 0; kt < nk; ++kt) {
    *(s16x8*)&lA[0][u0] = vah0; *(s16x8*)&lA[0][u1] = vah1;
    *(s16x8*)&lA[1][u0] = val0; *(s16x8*)&lA[1][u1] = val1;
    *(s16x8*)&lB[0][u0] = vbh0; *(s16x8*)&lB[0][u1] = vbh1;
    *(s16x8*)&lB[1][u0] = vbl0; *(s16x8*)&lB[1][u1] = vbl1;
    __syncthreads();
    if (kt + 1 < nk) LOADALL((size_t)(kt + 1) * 32);   // overlap with compute

    s16x8 afh[4], afl[4], bfh[4], bfl[4];
#pragma unroll
    for (int mi = 0; mi < 4; ++mi) {
      afh[mi] = *(const s16x8*)&lA[0][(wm + mi * 16) * 32 + aoff];
      afl[mi] = *(const s16x8*)&lA[1][(wm + mi * 16) * 32 + aoff];
    }
#pragma unroll
    for (int ni = 0; ni < 4; ++ni) {
      bfh[ni] = *(const s16x8*)&lB[0][(wn + ni * 16) * 32 + aoff];
      bfl[ni] = *(const s16x8*)&lB[1][(wn + ni * 16) * 32 + aoff];
    }
#pragma unroll
    for (int mi = 0; mi < 4; ++mi)
#pragma unroll
      for (int ni = 0; ni < 4; ++ni) {
        acc[mi][ni] = __builtin_amdgcn_mfma_f32_16x16x32_bf16(afh[mi], bfh[ni], acc[mi][ni], 0, 0, 0);
        acc[mi][ni] = __builtin_amdgcn_mfma_f32_16x16x32_bf16(afh[mi], bfl[ni], acc[mi][ni], 0, 0, 0);
        acc[mi][ni] = __builtin_amdgcn_mfma_f32_16x16x32_bf16(afl[mi], bfh[ni], acc[mi][ni], 0, 0, 0);
      }
    __syncthreads();
  }

  // epilogue: C row = (l>>4)*4 + j, col = l&15 within each 16x16 fragment
  const int colb = n0 + wn + (l & 15);
  const int rowb = m0 + wm + (l >> 4) * 4;
  if (EPI == 1) {
#pragma unroll
    for (int mi = 0; mi < 4; ++mi)
#pragma unroll
      for (int ni = 0; ni < 4; ++ni) {
        const int col = colb + ni * 16;
        const float bc = bias[col];
#pragma unroll
        for (int j = 0; j < 4; ++j) {
          const int row = rowb + mi * 16 + j;
          const float v = tanhf(acc[mi][ni][j] + bc);
          unsigned short hh, ll;
          split2(v, hh, ll);
          const size_t idx = (size_t)row * N + col;
          Yh[idx] = hh; Yl[idx] = ll;
        }
      }
  } else {
    float* dst = Fout + (EPI == 2 ? (size_t)blockIdx.z * (size_t)M * N : (size_t)0);
#pragma unroll
    for (int mi = 0; mi < 4; ++mi)
#pragma unroll
      for (int ni = 0; ni < 4; ++ni) {
        const int col = colb + ni * 16;
#pragma unroll
        for (int j = 0; j < 4; ++j) {
          const int row = rowb + mi * 16 + j;
          dst[(size_t)row * N + col] = acc[mi][ni][j];
        }
      }
  }
}

// ---------------------------------------------------------------------------
// reduce split-K partials. EPI=0: F = sum. EPI=1: tanh(sum+bias) -> Yh/Yl.
// ---------------------------------------------------------------------------
template<int EPI>
__global__ void reduce_k(const float* __restrict__ part, int S, int M, int N,
                         const float* __restrict__ bias,
                         float* __restrict__ F,
                         unsigned short* __restrict__ Yh, unsigned short* __restrict__ Yl)
{
  const size_t MN = (size_t)M * N;
  const size_t tot = MN >> 2;
  for (size_t i = (size_t)blockIdx.x * blockDim.x + threadIdx.x; i < tot;
       i += (size_t)gridDim.x * blockDim.x) {
    f32x4 s = *(const f32x4*)(part + 4 * i);
    for (int z = 1; z < S; ++z) s += *(const f32x4*)(part + (size_t)z * MN + 4 * i);
    if (EPI == 1) {
      const int col = (int)((4 * i) % (size_t)N);
      const f32x4 b = *(const f32x4*)(bias + col);
      u16x4 hh, ll;
#pragma unroll
      for (int j = 0; j < 4; ++j) {
        const float v = tanhf(s[j] + b[j]);
        unsigned short h_, l_;
        split2(v, h_, l_);
        hh[j] = h_; ll[j] = l_;
      }
      *(u16x4*)(Yh + 4 * i) = hh;
      *(u16x4*)(Yl + 4 * i) = ll;
    } else {
      *(f32x4*)(F + 4 * i) = s;
    }
  }
}

// ---------------------------------------------------------------------------
// v = A + (a_c + a_s*sdt)*Fv ; write dstF (fp32), optional hi/lo split,
// optional second fp32 copy dst2. sdt = (t_span[1]-t_span[0])/7.
// ---------------------------------------------------------------------------
__global__ void axpy_split_k(
    float* __restrict__ dstF, unsigned short* __restrict__ dstH,
    unsigned short* __restrict__ dstL, float* __restrict__ dst2,
    const float* __restrict__ A, const float* __restrict__ Fv,
    float a_c, float a_s, const float* __restrict__ tspan, int n4)
{
  const float sdt = (tspan[1] - tspan[0]) * (1.0f / 7.0f);
  const float coef = a_c + a_s * sdt;
  for (int i = blockIdx.x * blockDim.x + threadIdx.x; i < n4;
       i += gridDim.x * blockDim.x) {
    const size_t o = 4 * (size_t)i;
    const f32x4 a = *(const f32x4*)(A + o);
    const f32x4 f = *(const f32x4*)(Fv + o);
    f32x4 v = a + coef * f;
    *(f32x4*)(dstF + o) = v;
    if (dstH) {
      u16x4 hh, ll;
#pragma unroll
      for (int j = 0; j < 4; ++j) {
        unsigned short h_, l_;
        split2(v[j], h_, l_);
        hh[j] = h_; ll[j] = l_;
      }
      *(u16x4*)(dstH + o) = hh;
      *(u16x4*)(dstL + o) = ll;
    }
    if (dst2) *(f32x4*)(dst2 + o) = v;
  }
}

// ---------------------------------------------------------------------------
// RK4 bookkeeping: ACC = (add? ACC : X) + a1*sdt*F ; XT = X + a2*sdt*F
// (XT emitted only as hi/lo split - GEMM is its only consumer)
// ---------------------------------------------------------------------------
__global__ void rk_upd_k(
    float* __restrict__ ACC,
    unsigned short* __restrict__ XTh, unsigned short* __restrict__ XTl,
    const float* __restrict__ X, const float* __restrict__ Fv,
    float a1, float a2, int accAdd, const float* __restrict__ tspan, int n4)
{
  const float sdt = (tspan[1] - tspan[0]) * (1.0f / 7.0f);
  const float c1 = a1 * sdt, c2 = a2 * sdt;
  for (int i = blockIdx.x * blockDim.x + threadIdx.x; i < n4;
       i += gridDim.x * blockDim.x) {
    const size_t o = 4 * (size_t)i;
    const f32x4 x = *(const f32x4*)(X + o);
    const f32x4 f = *(const f32x4*)(Fv + o);
    f32x4 av;
    if (accAdd) av = *(const f32x4*)(ACC + o) + c1 * f;
    else        av = x + c1 * f;
    *(f32x4*)(ACC + o) = av;
    const f32x4 xt = x + c2 * f;
    u16x4 hh, ll;
#pragma unroll
    for (int j = 0; j < 4; ++j) {
      unsigned short h_, l_;
      split2(xt[j], h_, l_);
      hh[j] = h_; ll[j] = l_;
    }
    *(u16x4*)(XTh + o) = hh;
    *(u16x4*)(XTl + o) = ll;
  }
}

// ---------------------------------------------------------------------------
// W [K][N] fp32  ->  Th/Tl [N][K] bf16 hi/lo (one-time per launch)
// ---------------------------------------------------------------------------
__global__ void transpose_split_k(const float* __restrict__ W,
                                  unsigned short* __restrict__ Th,
                                  unsigned short* __restrict__ Tl,
                                  int K, int N)
{
  __shared__ float t[32][33];
  const int tx = threadIdx.x & 31, ty = threadIdx.x >> 5;
  const int n0 = blockIdx.x * 32, k0 = blockIdx.y * 32;
#pragma unroll
  for (int r = 0; r < 4; ++r) {
    const int row = ty + r * 8;
    t[row][tx] = W[(size_t)(k0 + row) * N + n0 + tx];
  }
  __syncthreads();
#pragma unroll
  for (int r = 0; r < 4; ++r) {
    const int row = ty + r * 8;
    const float v = t[tx][row];   // = W[k0+tx][n0+row]
    unsigned short hh, ll;
    split2(v, hh, ll);
    const size_t idx = (size_t)(n0 + row) * K + k0 + tx;
    Th[idx] = hh; Tl[idx] = ll;
  }
}

// ---------------------------------------------------------------------------
extern "C" void kernel_launch(void* const* d_in, const int* in_sizes, int n_in,
                              void* d_out, int out_size, void* d_ws, size_t ws_size,
                              hipStream_t stream)
{
  const float* Bin   = (const float*)d_in[0];
  const float* tspan = (const float*)d_in[1];
  const float* W1    = (const float*)d_in[2];
  const float* b1    = (const float*)d_in[3];
  const float* W2    = (const float*)d_in[4];

  const int n = in_sizes[1];                 // 16 sub-intervals
  const int h = in_sizes[3];                 // 4096
  const int d = in_sizes[2] / h;             // 1024
  const int batch = in_sizes[0] / (n * d);   // 256
  const int S = 7;                           // fine_steps-1 (setup: fine_steps=8)
  const int MAXIT = 2;                       // setup: maxiter=2
  const size_t NB = (size_t)batch * d;       // elems per node

  float* Bw = (float*)d_out;                 // working B lives in d_out

  uint8_t* wsb = (uint8_t*)d_ws;
  size_t off = 0;
  auto carve = [&](size_t bytes) -> void* {
    off = (off + 255) & ~(size_t)255;
    void* p = wsb + off;
    off += bytes;
    return p;
  };

  const size_t WH = (size_t)d * h;
  unsigned short* W1Th = (unsigned short*)carve(WH * 2);
  unsigned short* W1Tl = (unsigned short*)carve(WH * 2);
  unsigned short* W2Th = (unsigned short*)carve(WH * 2);
  unsigned short* W2Tl = (unsigned short*)carve(WH * 2);
  float* Dbuf = (float*)carve((size_t)(n - 1) * NB * 4);
  float* Part = (float*)carve((size_t)2 * batch * h * 4);  // split-K partials

  // adaptive node-chunk for the vectorized sweeps
  const size_t per_node = (size_t)batch * ((size_t)d * 28 + (size_t)h * 4);
  const size_t avail = ws_size > off + 8192 ? ws_size - off - 8192 : 0;
  int c = (int)(avail / per_node);
  if (c < 1) c = 1;
  if (c > n - 1) c = n - 1;
  const size_t CE = (size_t)c * NB;
  float*          Cst = (float*)carve(CE * 4);
  unsigned short* Csh = (unsigned short*)carve(CE * 2);
  unsigned short* Csl = (unsigned short*)carve(CE * 2);
  float*          Xf  = (float*)carve(CE * 4);
  unsigned short* Xh  = (unsigned short*)carve(CE * 2);
  unsigned short* Xl  = (unsigned short*)carve(CE * 2);
  unsigned short* XTh = (unsigned short*)carve(CE * 2);
  unsigned short* XTl = (unsigned short*)carve(CE * 2);
  float*          ACC = (float*)carve(CE * 4);
  float*          Fb  = (float*)carve(CE * 4);
  unsigned short* Yh  = (unsigned short*)carve((size_t)c * batch * h * 2);
  unsigned short* Yl  = (unsigned short*)carve((size_t)c * batch * h * 2);

  auto ewg = [](size_t n4) -> int {
    size_t g = (n4 + 255) / 256;
    if (g > 2048) g = 2048;
    if (g < 1) g = 1;
    return (int)g;
  };
  auto axpy = [&](float* dF, unsigned short* dH, unsigned short* dL, float* d2,
                  const float* A, const float* Fv, float ac, float as, size_t ne) {
    const int n4 = (int)(ne / 4);
    axpy_split_k<<<ewg(n4), 256, 0, stream>>>(dF, dH, dL, d2, A, Fv, ac, as, tspan, n4);
  };
  auto rkupd = [&](float a1, float a2, int add, size_t ne) {
    const int n4 = (int)(ne / 4);
    rk_upd_k<<<ewg(n4), 256, 0, stream>>>(ACC, XTh, XTl, Xf, Fb, a1, a2, add, tspan, n4);
  };
  auto feval = [&](const unsigned short* xh, const unsigned short* xl, int M) {
    gemm_split_k<1><<<dim3(h / 128, M / 128, 1), 256, 0, stream>>>(
        xh, xl, W1Th, W1Tl, b1, nullptr, Yh, Yl, M, h, d, d);
    gemm_split_k<0><<<dim3(d / 128, M / 128, 1), 256, 0, stream>>>(
        Yh, Yl, W2Th, W2Tl, nullptr, Fb, nullptr, nullptr, M, d, h, h);
  };
  auto feval_seq = [&](const unsigned short* xh, const unsigned short* xl) {
    const int M = batch;  // 256: split-K to keep dispatches wide & shallow
    gemm_split_k<2><<<dim3(h / 128, M / 128, 2), 256, 0, stream>>>(
        xh, xl, W1Th, W1Tl, nullptr, Part, nullptr, nullptr, M, h, d, d / 2);
    reduce_k<1><<<ewg((size_t)M * h / 4), 256, 0, stream>>>(Part, 2, M, h, b1, nullptr, Yh, Yl);
    gemm_split_k<2><<<dim3(d / 128, M / 128, 8), 256, 0, stream>>>(
        Yh, Yl, W2Th, W2Tl, nullptr, Part, nullptr, nullptr, M, d, h, h / 8);
    reduce_k<0><<<ewg((size_t)M * d / 4), 256, 0, stream>>>(Part, 8, M, d, nullptr, Fb, nullptr, nullptr);
  };

  // ---- prep: B -> d_out working copy; transpose+split weights -------------
  hipMemcpyAsync(Bw, Bin, (size_t)n * NB * 4, hipMemcpyDeviceToDevice, stream);
  transpose_split_k<<<dim3(h / 32, d / 32), 256, 0, stream>>>(W1, W1Th, W1Tl, d, h);
  transpose_split_k<<<dim3(d / 32, h / 32), 256, 0, stream>>>(W2, W2Th, W2Tl, h, d);

  // ---- Parareal outer loop: i = 1 .. maxiter+1 ----------------------------
  for (int i = 1; i <= MAXIT + 1; ++i) {
    const int rem = n - i;

    // vectorized coarse (Euler) + fine (RK4) over nodes i-1 .. n-2
    for (int base = 0; base < rem; base += c) {
      const int cc = (rem - base) < c ? (rem - base) : c;
      const int M = cc * batch;
      const size_t ne = (size_t)M * d;
      const float* src = Bw + (size_t)(i - 1 + base) * NB;

      // coarse: Cst <- src; 7x { F=f(Cst); Cst += sdt*F }
      axpy(Cst, Csh, Csl, nullptr, src, src, 0.f, 0.f, ne);
      for (int s = 0; s < S; ++s) {
        feval(Csh, Csl, M);
        axpy(Cst, Csh, Csl, nullptr, Cst, Fb, 0.f, 1.f, ne);
      }
      // fine: Xf <- src; 7x RK4
      axpy(Xf, Xh, Xl, nullptr, src, src, 0.f, 0.f, ne);
      for (int s = 0; s < S; ++s) {
        feval(Xh, Xl, M);                       // k1
        rkupd(1.f / 6.f, 0.5f, 0, ne);          // ACC = X+sdt/6 k1; XT = X+sdt/2 k1
        feval(XTh, XTl, M);                     // k2
        rkupd(1.f / 3.f, 0.5f, 1, ne);
        feval(XTh, XTl, M);                     // k3
        rkupd(1.f / 3.f, 1.0f, 1, ne);
        feval(XTh, XTl, M);                     // k4
        axpy(Xf, Xh, Xl, nullptr, ACC, Fb, 0.f, 1.f / 6.f, ne);  // X = ACC + sdt/6 k4
      }
      // D[base..] = fine - coarse
      axpy(Dbuf + (size_t)base * NB, nullptr, nullptr, nullptr, Xf, Cst, -1.f, 0.f, ne);
    }

    // sequential Parareal correction: x <- B[i-1]; for m: x = Euler(x) + D[m]
    const float* start = Bw + (size_t)(i - 1) * NB;
    axpy(Xf, Xh, Xl, nullptr, start, start, 0.f, 0.f, NB);
    for (int m = 0; m < rem; ++m) {
      for (int s = 0; s < S; ++s) {
        feval_seq(Xh, Xl);
        axpy(Xf, Xh, Xl, nullptr, Xf, Fb, 0.f, 1.f, NB);
      }
      axpy(Xf, Xh, Xl, Bw + (size_t)(i + m) * NB, Xf, Dbuf + (size_t)m * NB, 1.f, 0.f, NB);
    }
  }
}

// Round 2
// 46178.876 us; speedup vs baseline: 1.0155x; 1.0155x over previous
//
#include <hip/hip_runtime.h>
#include <cstdint>
#include <cstddef>

// ---------------------------------------------------------------------------
// Parareal neural-ODE (MSZero_13761075216509)
// f(x) = tanh(x@W1 + b1) @ W2 ; Euler coarse / RK4 fine, 7 substeps, 3 outer
// iterations. fp32 emulated via bf16 hi/lo 3-term split on 16x16x32 MFMA.
// R2: global_load_lds staging; coarse-sweep reuse from seq-phase Euler cache;
//     RK/Euler updates fused into GEMM2 epilogue; seq substep = 3 dispatches.
// ---------------------------------------------------------------------------

typedef __attribute__((ext_vector_type(4))) float f32x4;
typedef __attribute__((ext_vector_type(8))) short s16x8;
typedef __attribute__((ext_vector_type(4))) unsigned short u16x4;

#define DEV __device__ __forceinline__

DEV unsigned short f2bf(float x) {
  union { float f; uint32_t u; } v; v.f = x;
  uint32_t r = v.u + 0x7FFFu + ((v.u >> 16) & 1u);   // RNE
  return (unsigned short)(r >> 16);
}
DEV float bf2f(unsigned short h) {
  union { uint32_t u; float f; } v; v.u = ((uint32_t)h) << 16; return v.f;
}
DEV void split2(float x, unsigned short &h, unsigned short &l) {
  h = f2bf(x);
  l = f2bf(x - bf2f(h));
}
DEV float fast_tanh(float z) {
  // 1 - 2/(e^{2z}+1): monotone, safe at +-inf (no NaN), ~1e-7 rel err
  return 1.f - 2.f / (__expf(2.f * z) + 1.f);
}
DEV void gload16(const unsigned short* g, unsigned short* l) {
  __builtin_amdgcn_global_load_lds(
      (const __attribute__((address_space(1))) void*)g,
      (__attribute__((address_space(3))) void*)l, 16, 0, 0);
}

// ---------------------------------------------------------------------------
// GEMM: C[M,N] = A[M,K]*B[K,N]; A hi/lo bf16 [M][K], B pre-transposed hi/lo
// bf16 [N][K]. 3-term split: Ah*Bh + Ah*Bl + Al*Bh, fp32 MFMA accumulate.
// Staging: global_load_lds width 16, linear [128][32] LDS tiles (m97 pattern).
// EPI=1: v=tanh(acc+bias[col]) -> Oh/Ol bf16
// EPI=2: fp32 partial at Part + blockIdx.z*M*N (split-K)
// EPI=3: rk-update: a=(add?ACC:X)+a1*sdt*acc -> ACC ; xt=X+a2*sdt*acc -> Oh/Ol
// EPI=4: axpy-update: v=Xin+(a1+a2*sdt)*acc -> Xout fp32 + Oh/Ol split
// ---------------------------------------------------------------------------
template<int EPI>
__global__ __launch_bounds__(256, 2) void gemm_k(
    const unsigned short* __restrict__ Ah, const unsigned short* __restrict__ Al,
    const unsigned short* __restrict__ Bh, const unsigned short* __restrict__ Bl,
    const float* __restrict__ bias,
    float* __restrict__ Part,
    unsigned short* __restrict__ Oh, unsigned short* __restrict__ Ol,
    const float* __restrict__ Xin,
    float* __restrict__ ACCb,
    float* __restrict__ Xout,
    const float* __restrict__ tspan,
    float a1, float a2, int accAdd,
    int M, int N, int K, int KS)
{
  __shared__ unsigned short sA[2][128 * 32];   // [hi/lo][128 rows][32 k]
  __shared__ unsigned short sB[2][128 * 32];
  const int tid = threadIdx.x;
  const int w = tid >> 6, l = tid & 63;
  const int m0 = blockIdx.y * 128, n0 = blockIdx.x * 128;
  const size_t kbeg = (size_t)blockIdx.z * (size_t)KS;
  const int wm = (w >> 1) * 64, wn = (w & 1) * 64;

  f32x4 acc[4][4];
#pragma unroll
  for (int a = 0; a < 4; ++a)
#pragma unroll
    for (int b = 0; b < 4; ++b) acc[a][b] = (f32x4){0.f, 0.f, 0.f, 0.f};

  // per-lane global source: thread tid covers tile bytes [tid*16,+16) and
  // [tid*16+4096,+16) -> row r0 (+64), k-elems c0..c0+7
  const int o0 = tid * 16;
  const int r0 = o0 >> 6;
  const int c0 = (o0 & 63) >> 1;
  const size_t strideA = (size_t)64 * (size_t)K;
  const unsigned short* pah = Ah + (size_t)(m0 + r0) * K + kbeg + c0;
  const unsigned short* pal = Al + (size_t)(m0 + r0) * K + kbeg + c0;
  const unsigned short* pbh = Bh + (size_t)(n0 + r0) * K + kbeg + c0;
  const unsigned short* pbl = Bl + (size_t)(n0 + r0) * K + kbeg + c0;

  // wave-uniform LDS dest bases: wave w call j covers bytes w*1024 + j*4096
  const int wb = w * 512;   // ushort index
  unsigned short* dAh0 = &sA[0][wb]; unsigned short* dAh1 = &sA[0][wb + 2048];
  unsigned short* dAl0 = &sA[1][wb]; unsigned short* dAl1 = &sA[1][wb + 2048];
  unsigned short* dBh0 = &sB[0][wb]; unsigned short* dBh1 = &sB[0][wb + 2048];
  unsigned short* dBl0 = &sB[1][wb]; unsigned short* dBl1 = &sB[1][wb + 2048];

  const int nk = KS >> 5;
  const int aoff = (l & 15) * 32 + (l >> 4) * 8;

  for (int kt = 0; kt < nk; ++kt) {
    const size_t ko = (size_t)kt * 32;
    gload16(pah + ko, dAh0); gload16(pah + ko + strideA, dAh1);
    gload16(pal + ko, dAl0); gload16(pal + ko + strideA, dAl1);
    gload16(pbh + ko, dBh0); gload16(pbh + ko + strideA, dBh1);
    gload16(pbl + ko, dBl0); gload16(pbl + ko + strideA, dBl1);
    __syncthreads();                      // drains vmcnt -> LDS tiles ready

    s16x8 afh[4], afl[4], bfh[4], bfl[4];
#pragma unroll
    for (int mi = 0; mi < 4; ++mi) {
      afh[mi] = *(const s16x8*)&sA[0][(wm + mi * 16) * 32 + aoff];
      afl[mi] = *(const s16x8*)&sA[1][(wm + mi * 16) * 32 + aoff];
    }
#pragma unroll
    for (int ni = 0; ni < 4; ++ni) {
      bfh[ni] = *(const s16x8*)&sB[0][(wn + ni * 16) * 32 + aoff];
      bfl[ni] = *(const s16x8*)&sB[1][(wn + ni * 16) * 32 + aoff];
    }
#pragma unroll
    for (int mi = 0; mi < 4; ++mi)
#pragma unroll
      for (int ni = 0; ni < 4; ++ni) {
        acc[mi][ni] = __builtin_amdgcn_mfma_f32_16x16x32_bf16(afh[mi], bfh[ni], acc[mi][ni], 0, 0, 0);
        acc[mi][ni] = __builtin_amdgcn_mfma_f32_16x16x32_bf16(afh[mi], bfl[ni], acc[mi][ni], 0, 0, 0);
        acc[mi][ni] = __builtin_amdgcn_mfma_f32_16x16x32_bf16(afl[mi], bfh[ni], acc[mi][ni], 0, 0, 0);
      }
    __syncthreads();                      // before next-iter LDS overwrite
  }

  // epilogue: fragment (mi,ni) elem j -> row = wm+mi*16+(l>>4)*4+j, col = wn+ni*16+(l&15)
  const int colb = n0 + wn + (l & 15);
  const int rowb = m0 + wm + (l >> 4) * 4;
  const float sdt = (EPI >= 3) ? (tspan[1] - tspan[0]) * (1.0f / 7.0f) : 0.f;

  if (EPI == 1) {
#pragma unroll
    for (int mi = 0; mi < 4; ++mi)
#pragma unroll
      for (int ni = 0; ni < 4; ++ni) {
        const int col = colb + ni * 16;
        const float bc = bias[col];
#pragma unroll
        for (int j = 0; j < 4; ++j) {
          const size_t idx = (size_t)(rowb + mi * 16 + j) * N + col;
          const float v = fast_tanh(acc[mi][ni][j] + bc);
          unsigned short hh, ll; split2(v, hh, ll);
          Oh[idx] = hh; Ol[idx] = ll;
        }
      }
  } else if (EPI == 2) {
    float* dst = Part + (size_t)blockIdx.z * (size_t)M * N;
#pragma unroll
    for (int mi = 0; mi < 4; ++mi)
#pragma unroll
      for (int ni = 0; ni < 4; ++ni) {
        const int col = colb + ni * 16;
#pragma unroll
        for (int j = 0; j < 4; ++j)
          dst[(size_t)(rowb + mi * 16 + j) * N + col] = acc[mi][ni][j];
      }
  } else if (EPI == 3) {
    const float c1 = a1 * sdt, c2 = a2 * sdt;
#pragma unroll
    for (int mi = 0; mi < 4; ++mi)
#pragma unroll
      for (int ni = 0; ni < 4; ++ni) {
        const int col = colb + ni * 16;
#pragma unroll
        for (int j = 0; j < 4; ++j) {
          const size_t idx = (size_t)(rowb + mi * 16 + j) * N + col;
          const float f = acc[mi][ni][j];
          const float x = Xin[idx];
          const float a = (accAdd ? ACCb[idx] : x) + c1 * f;
          ACCb[idx] = a;
          const float xt = x + c2 * f;
          unsigned short hh, ll; split2(xt, hh, ll);
          Oh[idx] = hh; Ol[idx] = ll;
        }
      }
  } else {  // EPI == 4
    const float coef = a1 + a2 * sdt;
#pragma unroll
    for (int mi = 0; mi < 4; ++mi)
#pragma unroll
      for (int ni = 0; ni < 4; ++ni) {
        const int col = colb + ni * 16;
#pragma unroll
        for (int j = 0; j < 4; ++j) {
          const size_t idx = (size_t)(rowb + mi * 16 + j) * N + col;
          const float v = Xin[idx] + coef * acc[mi][ni][j];
          Xout[idx] = v;
          unsigned short hh, ll; split2(v, hh, ll);
          Oh[idx] = hh; Ol[idx] = ll;
        }
      }
  }
}

// ---------------------------------------------------------------------------
// fused split-K reduce + Euler update (+ optional Parareal correction):
// F = sum_z part[z]; E = X + sdt*F; [Eout=E]; v = E [+ Dv]; X=v (+hi/lo);
// [Bout=v]
// ---------------------------------------------------------------------------
__global__ void reduce_axpy_k(const float* __restrict__ part, int S, int MN4,
    const float* __restrict__ tspan,
    float* __restrict__ Xf, unsigned short* __restrict__ Xh, unsigned short* __restrict__ Xl,
    const float* __restrict__ Dv, float* __restrict__ Bout, float* __restrict__ Eout)
{
  const int i = blockIdx.x * blockDim.x + threadIdx.x;
  if (i >= MN4) return;
  const float sdt = (tspan[1] - tspan[0]) * (1.0f / 7.0f);
  const size_t MN = (size_t)MN4 * 4;
  const size_t o = 4 * (size_t)i;
  f32x4 s = *(const f32x4*)(part + o);
  for (int z = 1; z < S; ++z) s += *(const f32x4*)(part + (size_t)z * MN + o);
  f32x4 e = *(const f32x4*)(Xf + o) + sdt * s;
  if (Eout) *(f32x4*)(Eout + o) = e;
  f32x4 v = e;
  if (Dv) v += *(const f32x4*)(Dv + o);
  *(f32x4*)(Xf + o) = v;
  u16x4 hh, ll;
#pragma unroll
  for (int j = 0; j < 4; ++j) { unsigned short h_, l_; split2(v[j], h_, l_); hh[j] = h_; ll[j] = l_; }
  *(u16x4*)(Xh + o) = hh;
  *(u16x4*)(Xl + o) = ll;
  if (Bout) *(f32x4*)(Bout + o) = v;
}

// ---------------------------------------------------------------------------
// v = A + coef*Fv ; write dstF fp32, optional hi/lo split
// ---------------------------------------------------------------------------
__global__ void axpy_split_k(
    float* __restrict__ dstF, unsigned short* __restrict__ dstH,
    unsigned short* __restrict__ dstL,
    const float* __restrict__ A, const float* __restrict__ Fv,
    float coef, int n4)
{
  for (int i = blockIdx.x * blockDim.x + threadIdx.x; i < n4;
       i += gridDim.x * blockDim.x) {
    const size_t o = 4 * (size_t)i;
    const f32x4 a = *(const f32x4*)(A + o);
    const f32x4 f = *(const f32x4*)(Fv + o);
    f32x4 v = a + coef * f;
    *(f32x4*)(dstF + o) = v;
    if (dstH) {
      u16x4 hh, ll;
#pragma unroll
      for (int j = 0; j < 4; ++j) { unsigned short h_, l_; split2(v[j], h_, l_); hh[j] = h_; ll[j] = l_; }
      *(u16x4*)(dstH + o) = hh;
      *(u16x4*)(dstL + o) = ll;
    }
  }
}

// ---------------------------------------------------------------------------
// W [K][N] fp32 -> Th/Tl [N][K] bf16 hi/lo (once per launch)
// ---------------------------------------------------------------------------
__global__ void transpose_split_k(const float* __restrict__ W,
                                  unsigned short* __restrict__ Th,
                                  unsigned short* __restrict__ Tl,
                                  int K, int N)
{
  __shared__ float t[32][33];
  const int tx = threadIdx.x & 31, ty = threadIdx.x >> 5;
  const int n0 = blockIdx.x * 32, k0 = blockIdx.y * 32;
#pragma unroll
  for (int r = 0; r < 4; ++r) {
    const int row = ty + r * 8;
    t[row][tx] = W[(size_t)(k0 + row) * N + n0 + tx];
  }
  __syncthreads();
#pragma unroll
  for (int r = 0; r < 4; ++r) {
    const int row = ty + r * 8;
    const float v = t[tx][row];
    unsigned short hh, ll; split2(v, hh, ll);
    const size_t idx = (size_t)(n0 + row) * K + k0 + tx;
    Th[idx] = hh; Tl[idx] = ll;
  }
}

// ---------------------------------------------------------------------------
extern "C" void kernel_launch(void* const* d_in, const int* in_sizes, int n_in,
                              void* d_out, int out_size, void* d_ws, size_t ws_size,
                              hipStream_t stream)
{
  const float* Bin   = (const float*)d_in[0];
  const float* tspan = (const float*)d_in[1];
  const float* W1    = (const float*)d_in[2];
  const float* b1    = (const float*)d_in[3];
  const float* W2    = (const float*)d_in[4];

  const int n = in_sizes[1];                 // 16
  const int h = in_sizes[3];                 // 4096
  const int d = in_sizes[2] / h;             // 1024
  const int batch = in_sizes[0] / (n * d);   // 256
  const int S = 7;                           // fine_steps-1
  const int MAXIT = 2;
  const size_t NB = (size_t)batch * d;

  float* Bw = (float*)d_out;

  uint8_t* wsb = (uint8_t*)d_ws;
  size_t off = 0;
  auto carve = [&](size_t bytes) -> void* {
    off = (off + 255) & ~(size_t)255;
    void* p = wsb + off; off += bytes; return p;
  };

  const size_t WH = (size_t)d * h;
  unsigned short* W1Th = (unsigned short*)carve(WH * 2);
  unsigned short* W1Tl = (unsigned short*)carve(WH * 2);
  unsigned short* W2Th = (unsigned short*)carve(WH * 2);
  unsigned short* W2Tl = (unsigned short*)carve(WH * 2);
  float* Dbuf = (float*)carve((size_t)(n - 1) * NB * 4);
  float* Eb   = (float*)carve((size_t)n * NB * 4);   // cached seq-phase Euler outputs

  // split-K factor for seq GEMM2 + node chunk, sized to ws
  const size_t per_node = (size_t)batch * ((size_t)d * 24 + (size_t)h * 4);
  int SPL = 16;
  {
    size_t remb = ws_size > off + (1u << 20) ? ws_size - off - (1u << 20) : 0;
    while (SPL > 2 && (size_t)SPL * batch * d * 4 + per_node > remb) SPL >>= 1;
  }
  float* Part = (float*)carve((size_t)SPL * batch * d * 4);
  int c;
  {
    size_t remb = ws_size > off + (1u << 20) ? ws_size - off - (1u << 20) : 0;
    c = (int)(remb / per_node);
    if (c < 1) c = 1;
    if (c > n - 1) c = n - 1;
  }
  const size_t CE = (size_t)c * NB;
  float*          Cst = (float*)carve(CE * 4);
  unsigned short* Csh = (unsigned short*)carve(CE * 2);
  unsigned short* Csl = (unsigned short*)carve(CE * 2);
  float*          Xf  = (float*)carve(CE * 4);
  unsigned short* Xh  = (unsigned short*)carve(CE * 2);
  unsigned short* Xl  = (unsigned short*)carve(CE * 2);
  unsigned short* XTh = (unsigned short*)carve(CE * 2);
  unsigned short* XTl = (unsigned short*)carve(CE * 2);
  float*          ACC = (float*)carve(CE * 4);
  unsigned short* Yh  = (unsigned short*)carve((size_t)c * batch * h * 2);
  unsigned short* Yl  = (unsigned short*)carve((size_t)c * batch * h * 2);

  auto ewg = [](size_t n4) -> int {
    size_t g = (n4 + 255) / 256;
    if (g > 2048) g = 2048; if (g < 1) g = 1;
    return (int)g;
  };
  auto axpy = [&](float* dF, unsigned short* dH, unsigned short* dL,
                  const float* A, const float* Fv, float coef, size_t ne) {
    const int n4 = (int)(ne / 4);
    axpy_split_k<<<ewg(n4), 256, 0, stream>>>(dF, dH, dL, A, Fv, coef, n4);
  };
  // GEMM1: tanh epilogue -> Yh/Yl
  auto g1 = [&](const unsigned short* xh, const unsigned short* xl, int M) {
    gemm_k<1><<<dim3(h / 128, M / 128, 1), 256, 0, stream>>>(
        xh, xl, W1Th, W1Tl, b1, nullptr, Yh, Yl,
        nullptr, nullptr, nullptr, tspan, 0.f, 0.f, 0, M, h, d, d);
  };
  // GEMM2 + rk-update epilogue
  auto g2rk = [&](int M, float a1, float a2, int add) {
    gemm_k<3><<<dim3(d / 128, M / 128, 1), 256, 0, stream>>>(
        Yh, Yl, W2Th, W2Tl, nullptr, nullptr, XTh, XTl,
        Xf, ACC, nullptr, tspan, a1, a2, add, M, d, h, h);
  };
  // GEMM2 + axpy epilogue: dst = Xin + (a1 + a2*sdt)*F
  auto g2ax = [&](int M, float* dF, unsigned short* dH, unsigned short* dL,
                  const float* Xin, float a1, float a2) {
    gemm_k<4><<<dim3(d / 128, M / 128, 1), 256, 0, stream>>>(
        Yh, Yl, W2Th, W2Tl, nullptr, nullptr, dH, dL,
        Xin, nullptr, dF, tspan, a1, a2, 0, M, d, h, h);
  };

  // ---- prep ---------------------------------------------------------------
  hipMemcpyAsync(Bw, Bin, (size_t)n * NB * 4, hipMemcpyDeviceToDevice, stream);
  transpose_split_k<<<dim3(h / 32, d / 32), 256, 0, stream>>>(W1, W1Th, W1Tl, d, h);
  transpose_split_k<<<dim3(d / 32, h / 32), 256, 0, stream>>>(W2, W2Th, W2Tl, h, d);

  const int MN4 = (int)(NB / 4);

  // ---- Parareal outer loop ------------------------------------------------
  for (int i = 1; i <= MAXIT + 1; ++i) {
    const int rem = n - i;

    for (int base = 0; base < rem; base += c) {
      const int cc = (rem - base) < c ? (rem - base) : c;
      const int M = cc * batch;
      const size_t ne = (size_t)M * d;
      const int j0 = i - 1 + base;
      const float* src = Bw + (size_t)j0 * NB;

      if (i == 1) {
        // coarse Euler sweep (only needed on iteration 1; later iterations
        // reuse Eb from the previous sequential phase)
        axpy(Cst, Csh, Csl, src, src, 0.f, ne);
        for (int s = 0; s < S; ++s) {
          g1(Csh, Csl, M);
          g2ax(M, Cst, Csh, Csl, Cst, 0.f, 1.f);
        }
      }
      // fine RK4 sweep
      axpy(Xf, Xh, Xl, src, src, 0.f, ne);
      for (int s = 0; s < S; ++s) {
        g1(Xh, Xl, M);   g2rk(M, 1.f / 6.f, 0.5f, 0);   // k1
        g1(XTh, XTl, M); g2rk(M, 1.f / 3.f, 0.5f, 1);   // k2
        g1(XTh, XTl, M); g2rk(M, 1.f / 3.f, 1.0f, 1);   // k3
        g1(XTh, XTl, M); g2ax(M, Xf, Xh, Xl, ACC, 0.f, 1.f / 6.f);  // k4
      }
      // D = fine - coarse
      const float* Cref = (i == 1) ? Cst : (Eb + (size_t)j0 * NB);
      axpy(Dbuf + (size_t)base * NB, nullptr, nullptr, Xf, Cref, -1.f, ne);
    }

    // sequential Parareal correction; also caches Euler outputs into Eb
    const float* start = Bw + (size_t)(i - 1) * NB;
    axpy(Xf, Xh, Xl, start, start, 0.f, NB);
    for (int m = 0; m < rem; ++m) {
      for (int s = 0; s < S; ++s) {
        g1(Xh, Xl, batch);
        gemm_k<2><<<dim3(d / 128, batch / 128, SPL), 256, 0, stream>>>(
            Yh, Yl, W2Th, W2Tl, nullptr, Part, nullptr, nullptr,
            nullptr, nullptr, nullptr, tspan, 0.f, 0.f, 0, batch, d, h, h / SPL);
        const bool last = (s == S - 1);
        reduce_axpy_k<<<(MN4 + 255) / 256, 256, 0, stream>>>(
            Part, SPL, MN4, tspan, Xf, Xh, Xl,
            last ? Dbuf + (size_t)m * NB : nullptr,
            last ? Bw + (size_t)(i + m) * NB : nullptr,
            last ? Eb + (size_t)(i - 1 + m) * NB : nullptr);
      }
    }
  }
}